// Round 1
// baseline (358.360 us; speedup 1.0000x reference)
//
#include <hip/hip_runtime.h>

#define HW (384 * 384)      // 147456 per sample
#define BATCH 32
#define HW4 (HW / 4)        // 36864 float4 per sample
#define BLOCKS_PER_SAMPLE 144   // 144 * 256 threads * 4 elems = 147456

// stats layout in d_ws (4-byte slots):
//   [0..31]    fg_num  (float)
//   [32..63]   bg_num  (float)
//   [64..95]   num_fast (float)  = sum l_total*(fg+bg) per sample
//   [96..127]  den_fast (float)  = sum conf*(fg+bg) per sample
//   [128..159] thresh  (float)   (general path only)
//   [160..191] flag    (uint)    1 = fast path (hard == bg)
//   [192]      gnum    (float)
//   [193]      gden    (float)
#define S_FG 0
#define S_BG 32
#define S_NUMF 64
#define S_DENF 96
#define S_THR 128
#define S_FLAG 160
#define S_GNUM 192
#define S_GDEN 193

__device__ __forceinline__ void wave_reduce4(float& a, float& b, float& c, float& d) {
#pragma unroll
    for (int off = 32; off; off >>= 1) {
        a += __shfl_xor(a, off);
        b += __shfl_xor(b, off);
        c += __shfl_xor(c, off);
        d += __shfl_xor(d, off);
    }
}

// K1: one pass over all 7 arrays. Per-sample fg_num, bg_num, and speculative
// fast-path sums (train_mask = fg + bg).
__global__ __launch_bounds__(256) void k1_stats(
        const float4* __restrict__ rt, const float4* __restrict__ at,
        const float4* __restrict__ rp, const float4* __restrict__ ap,
        const float4* __restrict__ cf, const float4* __restrict__ fg,
        const float4* __restrict__ bg, float* __restrict__ stats) {
    const int b = blockIdx.y;
    const int idx = b * HW4 + blockIdx.x * 256 + threadIdx.x;
    float4 vrt = rt[idx], vat = at[idx], vrp = rp[idx], vap = ap[idx];
    float4 vcf = cf[idx], vfg = fg[idx], vbg = bg[idx];
    float sfg = 0.f, sbg = 0.f, snum = 0.f, sden = 0.f;
#pragma unroll
    for (int j = 0; j < 4; ++j) {
        float r = (&vrt.x)[j] - (&vrp.x)[j];
        float a = (&vat.x)[j] - (&vap.x)[j];
        float c = (&vcf.x)[j];
        float lt = (r * r + a * a) * c;
        float f = (&vfg.x)[j], g = (&vbg.x)[j];
        float train = f + g;
        sfg += f;
        sbg += g;
        snum += lt * train;
        sden += c * train;
    }
    wave_reduce4(sfg, sbg, snum, sden);
    if ((threadIdx.x & 63) == 0) {
        atomicAdd(&stats[S_FG + b], sfg);
        atomicAdd(&stats[S_BG + b], sbg);
        atomicAdd(&stats[S_NUMF + b], snum);
        atomicAdd(&stats[S_DENF + b], sden);
    }
}

// K2: one block per sample. Decide fast path (neg_num == bg_num -> hard == bg,
// proven exact) or run 4-pass radix-256 select for the exact k-th largest
// neg_loss value (uint bit pattern order == float order for non-negative).
__global__ __launch_bounds__(512) void k2_select(
        const float* __restrict__ rt, const float* __restrict__ at,
        const float* __restrict__ rp, const float* __restrict__ ap,
        const float* __restrict__ cf, const float* __restrict__ bg,
        float* __restrict__ stats) {
    const int b = blockIdx.x;
    const float fg_num = stats[S_FG + b];
    const float bg_num = stats[S_BG + b];
    int neg = (int)(fg_num * 3.0f);
    if (neg < 10000) neg = 10000;
    const int bgn = (int)bg_num;
    unsigned* flags = (unsigned*)stats;
    if (neg >= bgn) {
        // neg_num == bg_num: thresh is min bg loss (or 0) -> hard == bg exactly.
        if (threadIdx.x == 0) {
            flags[S_FLAG + b] = 1u;
            atomicAdd(&stats[S_GNUM], stats[S_NUMF + b]);
            atomicAdd(&stats[S_GDEN], stats[S_DENF + b]);
        }
        return;
    }
    if (threadIdx.x == 0) flags[S_FLAG + b] = 0u;

    __shared__ unsigned hist[256];
    __shared__ unsigned sh_prefix, sh_k;
    unsigned prefix = 0;
    unsigned k = (unsigned)neg;  // k >= 10000 >= 1 here
    const long base = (long)b * HW;
#pragma unroll 1
    for (int p = 3; p >= 0; --p) {
        for (int i = threadIdx.x; i < 256; i += blockDim.x) hist[i] = 0u;
        __syncthreads();
        const unsigned shift = 8u * (unsigned)p;
        const unsigned himask = (p == 3) ? 0u : (0xFFFFFFFFu << (shift + 8u));
#pragma unroll 1
        for (int i = threadIdx.x; i < HW; i += blockDim.x) {
            long g = base + i;
            float r = rt[g] - rp[g];
            float a = at[g] - ap[g];
            float lt = (r * r + a * a) * cf[g];
            float nl = lt * bg[g];
            unsigned v = __float_as_uint(nl);
            if ((v & himask) == prefix) atomicAdd(&hist[(v >> shift) & 255u], 1u);
        }
        __syncthreads();
        if (threadIdx.x == 0) {
            unsigned cum = 0;
            for (int bin = 255; bin >= 0; --bin) {
                unsigned c = hist[bin];
                if (cum + c >= k) {
                    sh_prefix = prefix | ((unsigned)bin << shift);
                    sh_k = k - cum;  // remaining rank within this bin
                    break;
                }
                cum += c;
            }
        }
        __syncthreads();
        prefix = sh_prefix;
        k = sh_k;
        __syncthreads();  // protect hist before next-pass zeroing
    }
    if (threadIdx.x == 0) stats[S_THR + b] = __uint_as_float(prefix);
}

// K3: masked sums for general-path samples only (early-exit on fast flag).
__global__ __launch_bounds__(256) void k3_general(
        const float4* __restrict__ rt, const float4* __restrict__ at,
        const float4* __restrict__ rp, const float4* __restrict__ ap,
        const float4* __restrict__ cf, const float4* __restrict__ fg,
        const float4* __restrict__ bg, float* __restrict__ stats) {
    const int b = blockIdx.y;
    if (((const unsigned*)stats)[S_FLAG + b] != 0u) return;
    const float thresh = stats[S_THR + b];
    const int idx = b * HW4 + blockIdx.x * 256 + threadIdx.x;
    float4 vrt = rt[idx], vat = at[idx], vrp = rp[idx], vap = ap[idx];
    float4 vcf = cf[idx], vfg = fg[idx], vbg = bg[idx];
    float snum = 0.f, sden = 0.f, z0 = 0.f, z1 = 0.f;
#pragma unroll
    for (int j = 0; j < 4; ++j) {
        float r = (&vrt.x)[j] - (&vrp.x)[j];
        float a = (&vat.x)[j] - (&vap.x)[j];
        float c = (&vcf.x)[j];
        float lt = (r * r + a * a) * c;
        float f = (&vfg.x)[j], g = (&vbg.x)[j];
        float nl = lt * g;
        float hard = (g != 0.f && nl >= thresh) ? 1.f : 0.f;
        float train = hard + f;
        snum += lt * train;
        sden += c * train;
    }
    wave_reduce4(snum, sden, z0, z1);
    if ((threadIdx.x & 63) == 0) {
        atomicAdd(&stats[S_GNUM], snum);
        atomicAdd(&stats[S_GDEN], sden);
    }
}

__global__ void k4_final(const float* __restrict__ stats, float* __restrict__ out) {
    out[0] = stats[S_GNUM] / (stats[S_GDEN] + 1e-7f);
}

extern "C" void kernel_launch(void* const* d_in, const int* in_sizes, int n_in,
                              void* d_out, int out_size, void* d_ws, size_t ws_size,
                              hipStream_t stream) {
    const float* rt = (const float*)d_in[0];
    const float* at = (const float*)d_in[1];
    const float* rp = (const float*)d_in[2];
    const float* ap = (const float*)d_in[3];
    const float* cf = (const float*)d_in[4];
    const float* fg = (const float*)d_in[5];
    const float* bg = (const float*)d_in[6];
    float* stats = (float*)d_ws;
    float* out = (float*)d_out;

    hipMemsetAsync(d_ws, 0, 1024, stream);

    dim3 grid(BLOCKS_PER_SAMPLE, BATCH);
    k1_stats<<<grid, 256, 0, stream>>>((const float4*)rt, (const float4*)at,
                                       (const float4*)rp, (const float4*)ap,
                                       (const float4*)cf, (const float4*)fg,
                                       (const float4*)bg, stats);
    k2_select<<<BATCH, 512, 0, stream>>>(rt, at, rp, ap, cf, bg, stats);
    k3_general<<<grid, 256, 0, stream>>>((const float4*)rt, (const float4*)at,
                                         (const float4*)rp, (const float4*)ap,
                                         (const float4*)cf, (const float4*)fg,
                                         (const float4*)bg, stats);
    k4_final<<<1, 1, 0, stream>>>(stats, out);
}

// Round 2
// 191.001 us; speedup vs baseline: 1.8762x; 1.8762x over previous
//
#include <hip/hip_runtime.h>

#define HW (384 * 384)      // 147456 per sample
#define BATCH 32
#define HW4 (HW / 4)        // 36864 float4 per sample
#define BLOCKS_PER_SAMPLE 144   // 144 * 256 threads * 4 elems = 147456

// stats layout in d_ws (4-byte slots):
//   [0..31]    fg_num  (float)
//   [32..63]   bg_num  (float)
//   [64..95]   num_fast (float)  = sum l_total*(fg+bg) per sample
//   [96..127]  den_fast (float)  = sum conf*(fg+bg) per sample
//   [128..159] thresh  (float)   (general path only)
//   [160..191] flag    (uint)    1 = fast path (hard == bg)
//   [192]      gnum    (float)
//   [193]      gden    (float)
#define S_FG 0
#define S_BG 32
#define S_NUMF 64
#define S_DENF 96
#define S_THR 128
#define S_FLAG 160
#define S_GNUM 192
#define S_GDEN 193

// Native device-scope fp32 atomic add (global_atomic_add_f32), avoiding the
// CAS retry loop hipcc emits for plain atomicAdd(float*) without
// -munsafe-fp-atomics. d_ws is coarse-grained device memory -> HW atomic valid.
__device__ __forceinline__ void fadd_agent(float* p, float v) {
    __hip_atomic_fetch_add(p, v, __ATOMIC_RELAXED, __HIP_MEMORY_SCOPE_AGENT);
}

__device__ __forceinline__ void wave_reduce4(float& a, float& b, float& c, float& d) {
#pragma unroll
    for (int off = 32; off; off >>= 1) {
        a += __shfl_xor(a, off);
        b += __shfl_xor(b, off);
        c += __shfl_xor(c, off);
        d += __shfl_xor(d, off);
    }
}

// K1: one pass over all 7 arrays. Per-sample fg_num, bg_num, and speculative
// fast-path sums (train_mask = fg + bg). Block-stage in LDS -> 4 native
// atomics per block (was 16 CAS-loop atomics -> 233us storm in R0).
__global__ __launch_bounds__(256) void k1_stats(
        const float4* __restrict__ rt, const float4* __restrict__ at,
        const float4* __restrict__ rp, const float4* __restrict__ ap,
        const float4* __restrict__ cf, const float4* __restrict__ fg,
        const float4* __restrict__ bg, float* __restrict__ stats) {
    const int b = blockIdx.y;
    const int idx = b * HW4 + blockIdx.x * 256 + threadIdx.x;
    float4 vrt = rt[idx], vat = at[idx], vrp = rp[idx], vap = ap[idx];
    float4 vcf = cf[idx], vfg = fg[idx], vbg = bg[idx];
    float sfg = 0.f, sbg = 0.f, snum = 0.f, sden = 0.f;
#pragma unroll
    for (int j = 0; j < 4; ++j) {
        float r = (&vrt.x)[j] - (&vrp.x)[j];
        float a = (&vat.x)[j] - (&vap.x)[j];
        float c = (&vcf.x)[j];
        float lt = (r * r + a * a) * c;
        float f = (&vfg.x)[j], g = (&vbg.x)[j];
        float train = f + g;
        sfg += f;
        sbg += g;
        snum += lt * train;
        sden += c * train;
    }
    wave_reduce4(sfg, sbg, snum, sden);
    __shared__ float sh[4][4];
    const int wave = threadIdx.x >> 6;
    if ((threadIdx.x & 63) == 0) {
        sh[wave][0] = sfg; sh[wave][1] = sbg; sh[wave][2] = snum; sh[wave][3] = sden;
    }
    __syncthreads();
    if (threadIdx.x < 4) {
        const int q = threadIdx.x;
        float s = sh[0][q] + sh[1][q] + sh[2][q] + sh[3][q];
        fadd_agent(&stats[q * 32 + b], s);   // q*32: S_FG/S_BG/S_NUMF/S_DENF
    }
}

// K2: one block per sample. Decide fast path (neg_num == bg_num -> hard == bg,
// proven exact) or run 4-pass radix-256 select for the exact k-th largest
// neg_loss value (uint bit pattern order == float order for non-negative).
__global__ __launch_bounds__(512) void k2_select(
        const float* __restrict__ rt, const float* __restrict__ at,
        const float* __restrict__ rp, const float* __restrict__ ap,
        const float* __restrict__ cf, const float* __restrict__ bg,
        float* __restrict__ stats) {
    const int b = blockIdx.x;
    const float fg_num = stats[S_FG + b];
    const float bg_num = stats[S_BG + b];
    int neg = (int)(fg_num * 3.0f);
    if (neg < 10000) neg = 10000;
    const int bgn = (int)bg_num;
    unsigned* flags = (unsigned*)stats;
    if (neg >= bgn) {
        // neg_num == bg_num: thresh is min bg loss (or 0) -> hard == bg exactly.
        if (threadIdx.x == 0) {
            flags[S_FLAG + b] = 1u;
            fadd_agent(&stats[S_GNUM], stats[S_NUMF + b]);
            fadd_agent(&stats[S_GDEN], stats[S_DENF + b]);
        }
        return;
    }
    if (threadIdx.x == 0) flags[S_FLAG + b] = 0u;

    __shared__ unsigned hist[256];
    __shared__ unsigned sh_prefix, sh_k;
    unsigned prefix = 0;
    unsigned k = (unsigned)neg;  // k >= 10000 >= 1 here
    const long base = (long)b * HW;
#pragma unroll 1
    for (int p = 3; p >= 0; --p) {
        for (int i = threadIdx.x; i < 256; i += blockDim.x) hist[i] = 0u;
        __syncthreads();
        const unsigned shift = 8u * (unsigned)p;
        const unsigned himask = (p == 3) ? 0u : (0xFFFFFFFFu << (shift + 8u));
#pragma unroll 1
        for (int i = threadIdx.x; i < HW; i += blockDim.x) {
            long g = base + i;
            float r = rt[g] - rp[g];
            float a = at[g] - ap[g];
            float lt = (r * r + a * a) * cf[g];
            float nl = lt * bg[g];
            unsigned v = __float_as_uint(nl);
            if ((v & himask) == prefix) atomicAdd(&hist[(v >> shift) & 255u], 1u);
        }
        __syncthreads();
        if (threadIdx.x == 0) {
            unsigned cum = 0;
            for (int bin = 255; bin >= 0; --bin) {
                unsigned c = hist[bin];
                if (cum + c >= k) {
                    sh_prefix = prefix | ((unsigned)bin << shift);
                    sh_k = k - cum;  // remaining rank within this bin
                    break;
                }
                cum += c;
            }
        }
        __syncthreads();
        prefix = sh_prefix;
        k = sh_k;
        __syncthreads();  // protect hist before next-pass zeroing
    }
    if (threadIdx.x == 0) stats[S_THR + b] = __uint_as_float(prefix);
}

// K3: masked sums for general-path samples only (early-exit on fast flag).
__global__ __launch_bounds__(256) void k3_general(
        const float4* __restrict__ rt, const float4* __restrict__ at,
        const float4* __restrict__ rp, const float4* __restrict__ ap,
        const float4* __restrict__ cf, const float4* __restrict__ fg,
        const float4* __restrict__ bg, float* __restrict__ stats) {
    const int b = blockIdx.y;
    if (((const unsigned*)stats)[S_FLAG + b] != 0u) return;
    const float thresh = stats[S_THR + b];
    const int idx = b * HW4 + blockIdx.x * 256 + threadIdx.x;
    float4 vrt = rt[idx], vat = at[idx], vrp = rp[idx], vap = ap[idx];
    float4 vcf = cf[idx], vfg = fg[idx], vbg = bg[idx];
    float snum = 0.f, sden = 0.f, z0 = 0.f, z1 = 0.f;
#pragma unroll
    for (int j = 0; j < 4; ++j) {
        float r = (&vrt.x)[j] - (&vrp.x)[j];
        float a = (&vat.x)[j] - (&vap.x)[j];
        float c = (&vcf.x)[j];
        float lt = (r * r + a * a) * c;
        float f = (&vfg.x)[j], g = (&vbg.x)[j];
        float nl = lt * g;
        float hard = (g != 0.f && nl >= thresh) ? 1.f : 0.f;
        float train = hard + f;
        snum += lt * train;
        sden += c * train;
    }
    wave_reduce4(snum, sden, z0, z1);
    __shared__ float sh[4][2];
    const int wave = threadIdx.x >> 6;
    if ((threadIdx.x & 63) == 0) { sh[wave][0] = snum; sh[wave][1] = sden; }
    __syncthreads();
    if (threadIdx.x < 2) {
        const int q = threadIdx.x;
        float s = sh[0][q] + sh[1][q] + sh[2][q] + sh[3][q];
        fadd_agent(&stats[S_GNUM + q], s);
    }
}

__global__ void k4_final(const float* __restrict__ stats, float* __restrict__ out) {
    out[0] = stats[S_GNUM] / (stats[S_GDEN] + 1e-7f);
}

extern "C" void kernel_launch(void* const* d_in, const int* in_sizes, int n_in,
                              void* d_out, int out_size, void* d_ws, size_t ws_size,
                              hipStream_t stream) {
    const float* rt = (const float*)d_in[0];
    const float* at = (const float*)d_in[1];
    const float* rp = (const float*)d_in[2];
    const float* ap = (const float*)d_in[3];
    const float* cf = (const float*)d_in[4];
    const float* fg = (const float*)d_in[5];
    const float* bg = (const float*)d_in[6];
    float* stats = (float*)d_ws;
    float* out = (float*)d_out;

    hipMemsetAsync(d_ws, 0, 1024, stream);

    dim3 grid(BLOCKS_PER_SAMPLE, BATCH);
    k1_stats<<<grid, 256, 0, stream>>>((const float4*)rt, (const float4*)at,
                                       (const float4*)rp, (const float4*)ap,
                                       (const float4*)cf, (const float4*)fg,
                                       (const float4*)bg, stats);
    k2_select<<<BATCH, 512, 0, stream>>>(rt, at, rp, ap, cf, bg, stats);
    k3_general<<<grid, 256, 0, stream>>>((const float4*)rt, (const float4*)at,
                                         (const float4*)rp, (const float4*)ap,
                                         (const float4*)cf, (const float4*)fg,
                                         (const float4*)bg, stats);
    k4_final<<<1, 1, 0, stream>>>(stats, out);
}

// Round 3
// 166.461 us; speedup vs baseline: 2.1528x; 1.1474x over previous
//
#include <hip/hip_runtime.h>

#define HW (384 * 384)      // 147456 per sample
#define BATCH 32
#define HW4 (HW / 4)        // 36864 float4 per sample
#define ITER 4              // float4 chunks per thread in k1/k3
#define BLOCKS_PER_SAMPLE 36    // 36 * 256 threads * 4 elems * ITER = 147456

// stats layout in d_ws (4-byte slots):
//   [0..31]    fg_num  (float)
//   [32..63]   bg_num  (float)
//   [64..95]   num_fast (float)  = sum l_total*(fg+bg) per sample
//   [96..127]  den_fast (float)  = sum conf*(fg+bg) per sample
//   [128..159] thresh  (float)   (general path only)
//   [160..191] flag    (uint)    1 = fast path (hard == bg)
//   [192]      gnum    (float)
//   [193]      gden    (float)
#define S_FG 0
#define S_BG 32
#define S_NUMF 64
#define S_DENF 96
#define S_THR 128
#define S_FLAG 160
#define S_GNUM 192
#define S_GDEN 193

// Native device-scope fp32 atomic add (global_atomic_add_f32), avoiding the
// CAS retry loop hipcc emits for plain atomicAdd(float*) without
// -munsafe-fp-atomics (R0->R1: 233us -> 66us).
__device__ __forceinline__ void fadd_agent(float* p, float v) {
    __hip_atomic_fetch_add(p, v, __ATOMIC_RELAXED, __HIP_MEMORY_SCOPE_AGENT);
}

__device__ __forceinline__ void wave_reduce4(float& a, float& b, float& c, float& d) {
#pragma unroll
    for (int off = 32; off; off >>= 1) {
        a += __shfl_xor(a, off);
        b += __shfl_xor(b, off);
        c += __shfl_xor(c, off);
        d += __shfl_xor(d, off);
    }
}

// K1: one pass over all 7 arrays. Per-sample fg_num, bg_num, and speculative
// fast-path sums (train_mask = fg + bg). R2: ITER=4 unrolled chunks per
// thread -> 28 independent loads in flight, reduce tail amortized 4x
// (R1 showed ~2200 cy/wave serialization from per-112B reduce tails).
__global__ __launch_bounds__(256) void k1_stats(
        const float4* __restrict__ rt, const float4* __restrict__ at,
        const float4* __restrict__ rp, const float4* __restrict__ ap,
        const float4* __restrict__ cf, const float4* __restrict__ fg,
        const float4* __restrict__ bg, float* __restrict__ stats) {
    const int b = blockIdx.y;
    const int base = b * HW4 + blockIdx.x * (256 * ITER) + threadIdx.x;
    float sfg = 0.f, sbg = 0.f, snum = 0.f, sden = 0.f;
#pragma unroll
    for (int it = 0; it < ITER; ++it) {
        const int idx = base + it * 256;
        float4 vrt = rt[idx], vat = at[idx], vrp = rp[idx], vap = ap[idx];
        float4 vcf = cf[idx], vfg = fg[idx], vbg = bg[idx];
#pragma unroll
        for (int j = 0; j < 4; ++j) {
            float r = (&vrt.x)[j] - (&vrp.x)[j];
            float a = (&vat.x)[j] - (&vap.x)[j];
            float c = (&vcf.x)[j];
            float lt = (r * r + a * a) * c;
            float f = (&vfg.x)[j], g = (&vbg.x)[j];
            float train = f + g;
            sfg += f;
            sbg += g;
            snum += lt * train;
            sden += c * train;
        }
    }
    wave_reduce4(sfg, sbg, snum, sden);
    __shared__ float sh[4][4];
    const int wave = threadIdx.x >> 6;
    if ((threadIdx.x & 63) == 0) {
        sh[wave][0] = sfg; sh[wave][1] = sbg; sh[wave][2] = snum; sh[wave][3] = sden;
    }
    __syncthreads();
    if (threadIdx.x < 4) {
        const int q = threadIdx.x;
        float s = sh[0][q] + sh[1][q] + sh[2][q] + sh[3][q];
        fadd_agent(&stats[q * 32 + b], s);   // q*32: S_FG/S_BG/S_NUMF/S_DENF
    }
}

// K2: one block per sample. Decide fast path (neg_num == bg_num -> hard == bg,
// proven exact) or run 4-pass radix-256 select for the exact k-th largest
// neg_loss value (uint bit pattern order == float order for non-negative).
__global__ __launch_bounds__(512) void k2_select(
        const float* __restrict__ rt, const float* __restrict__ at,
        const float* __restrict__ rp, const float* __restrict__ ap,
        const float* __restrict__ cf, const float* __restrict__ bg,
        float* __restrict__ stats) {
    const int b = blockIdx.x;
    const float fg_num = stats[S_FG + b];
    const float bg_num = stats[S_BG + b];
    int neg = (int)(fg_num * 3.0f);
    if (neg < 10000) neg = 10000;
    const int bgn = (int)bg_num;
    unsigned* flags = (unsigned*)stats;
    if (neg >= bgn) {
        // neg_num == bg_num: thresh is min bg loss (or 0) -> hard == bg exactly.
        if (threadIdx.x == 0) {
            flags[S_FLAG + b] = 1u;
            fadd_agent(&stats[S_GNUM], stats[S_NUMF + b]);
            fadd_agent(&stats[S_GDEN], stats[S_DENF + b]);
        }
        return;
    }
    if (threadIdx.x == 0) flags[S_FLAG + b] = 0u;

    __shared__ unsigned hist[256];
    __shared__ unsigned sh_prefix, sh_k;
    unsigned prefix = 0;
    unsigned k = (unsigned)neg;  // k >= 10000 >= 1 here
    const long base = (long)b * HW;
#pragma unroll 1
    for (int p = 3; p >= 0; --p) {
        for (int i = threadIdx.x; i < 256; i += blockDim.x) hist[i] = 0u;
        __syncthreads();
        const unsigned shift = 8u * (unsigned)p;
        const unsigned himask = (p == 3) ? 0u : (0xFFFFFFFFu << (shift + 8u));
#pragma unroll 1
        for (int i = threadIdx.x; i < HW; i += blockDim.x) {
            long g = base + i;
            float r = rt[g] - rp[g];
            float a = at[g] - ap[g];
            float lt = (r * r + a * a) * cf[g];
            float nl = lt * bg[g];
            unsigned v = __float_as_uint(nl);
            if ((v & himask) == prefix) atomicAdd(&hist[(v >> shift) & 255u], 1u);
        }
        __syncthreads();
        if (threadIdx.x == 0) {
            unsigned cum = 0;
            for (int bin = 255; bin >= 0; --bin) {
                unsigned c = hist[bin];
                if (cum + c >= k) {
                    sh_prefix = prefix | ((unsigned)bin << shift);
                    sh_k = k - cum;  // remaining rank within this bin
                    break;
                }
                cum += c;
            }
        }
        __syncthreads();
        prefix = sh_prefix;
        k = sh_k;
        __syncthreads();  // protect hist before next-pass zeroing
    }
    if (threadIdx.x == 0) stats[S_THR + b] = __uint_as_float(prefix);
}

// K3: masked sums for general-path samples only (early-exit on fast flag).
__global__ __launch_bounds__(256) void k3_general(
        const float4* __restrict__ rt, const float4* __restrict__ at,
        const float4* __restrict__ rp, const float4* __restrict__ ap,
        const float4* __restrict__ cf, const float4* __restrict__ fg,
        const float4* __restrict__ bg, float* __restrict__ stats) {
    const int b = blockIdx.y;
    if (((const unsigned*)stats)[S_FLAG + b] != 0u) return;
    const float thresh = stats[S_THR + b];
    const int base = b * HW4 + blockIdx.x * (256 * ITER) + threadIdx.x;
    float snum = 0.f, sden = 0.f, z0 = 0.f, z1 = 0.f;
#pragma unroll
    for (int it = 0; it < ITER; ++it) {
        const int idx = base + it * 256;
        float4 vrt = rt[idx], vat = at[idx], vrp = rp[idx], vap = ap[idx];
        float4 vcf = cf[idx], vfg = fg[idx], vbg = bg[idx];
#pragma unroll
        for (int j = 0; j < 4; ++j) {
            float r = (&vrt.x)[j] - (&vrp.x)[j];
            float a = (&vat.x)[j] - (&vap.x)[j];
            float c = (&vcf.x)[j];
            float lt = (r * r + a * a) * c;
            float f = (&vfg.x)[j], g = (&vbg.x)[j];
            float nl = lt * g;
            float hard = (g != 0.f && nl >= thresh) ? 1.f : 0.f;
            float train = hard + f;
            snum += lt * train;
            sden += c * train;
        }
    }
    wave_reduce4(snum, sden, z0, z1);
    __shared__ float sh[4][2];
    const int wave = threadIdx.x >> 6;
    if ((threadIdx.x & 63) == 0) { sh[wave][0] = snum; sh[wave][1] = sden; }
    __syncthreads();
    if (threadIdx.x < 2) {
        const int q = threadIdx.x;
        float s = sh[0][q] + sh[1][q] + sh[2][q] + sh[3][q];
        fadd_agent(&stats[S_GNUM + q], s);
    }
}

__global__ void k4_final(const float* __restrict__ stats, float* __restrict__ out) {
    out[0] = stats[S_GNUM] / (stats[S_GDEN] + 1e-7f);
}

extern "C" void kernel_launch(void* const* d_in, const int* in_sizes, int n_in,
                              void* d_out, int out_size, void* d_ws, size_t ws_size,
                              hipStream_t stream) {
    const float* rt = (const float*)d_in[0];
    const float* at = (const float*)d_in[1];
    const float* rp = (const float*)d_in[2];
    const float* ap = (const float*)d_in[3];
    const float* cf = (const float*)d_in[4];
    const float* fg = (const float*)d_in[5];
    const float* bg = (const float*)d_in[6];
    float* stats = (float*)d_ws;
    float* out = (float*)d_out;

    hipMemsetAsync(d_ws, 0, 1024, stream);

    dim3 grid(BLOCKS_PER_SAMPLE, BATCH);
    k1_stats<<<grid, 256, 0, stream>>>((const float4*)rt, (const float4*)at,
                                       (const float4*)rp, (const float4*)ap,
                                       (const float4*)cf, (const float4*)fg,
                                       (const float4*)bg, stats);
    k2_select<<<BATCH, 512, 0, stream>>>(rt, at, rp, ap, cf, bg, stats);
    k3_general<<<grid, 256, 0, stream>>>((const float4*)rt, (const float4*)at,
                                         (const float4*)rp, (const float4*)ap,
                                         (const float4*)cf, (const float4*)fg,
                                         (const float4*)bg, stats);
    k4_final<<<1, 1, 0, stream>>>(stats, out);
}